// Round 6
// baseline (161.601 us; speedup 1.0000x reference)
//
#include <hip/hip_runtime.h>
#include <hip/hip_bf16.h>
#include <hip/hip_cooperative_groups.h>

namespace cg = cooperative_groups;

// AgentModel: B=8, N=256, TD=128, LH=128, H=128, A=5, L=2
constexpr int Nc = 256;
constexpr int Hc = 128;
constexpr int Ac = 5;
constexpr int Mc = 2048;   // B*N
constexpr int R = 8;       // rows per block; grid = 2048/8 = 256 = #CUs

struct P {
  const float *theta, *cell, *encW, *encb, *msgW, *msgb, *updW, *updb;
  const float *hW1, *hb1, *hW2, *hb2;
  float *out;
  float *pjA, *pjB;                  // global ping-pong (cross-block)
  float *encWt, *Mt, *updWt, *hW1t;  // transposed weights (ws)
};

// One block = one CU = 8 rows. h, pi, z live in LDS for the whole model.
__global__ __launch_bounds__(512, 2) void fused(P p) {
  cg::grid_group grid = cg::this_grid();
  __shared__ float xs[R][256];   // enc input staging; cols<128 reused as h+agg
  __shared__ float hs[R][Hc];    // current h (block's 8 rows)
  __shared__ float pis[R][Hc];   // pi for block's rows
  __shared__ float zs[R][Hc];    // head z

  const int tid = threadIdx.x;
  const int m0 = blockIdx.x * R;       // global row base
  const int b = m0 >> 8;               // batch
  const int o = tid & 127;             // output col (H space)
  const int rg = tid >> 7;             // 0..3 -> rows rg*2, rg*2+1
  const int r0 = rg * 2;

  // ---- S0: transpose weights (grid-strided, ~1.13 elems/thread) -----------
  for (int id = blockIdx.x * 512 + tid; id < 147456; id += 131072) {
    if (id < 32768) {                       // encWt[k][o] = encW[o][k]
      int k = id >> 7, oo = id & 127;
      p.encWt[id] = p.encW[oo * 256 + k];
    } else if (id < 98304) {                // Mt[l][k][c]
      int e = id - 32768;
      int l = e >> 15, rr = e & 32767;
      int k = rr >> 8, c = rr & 255;
      p.Mt[e] = p.msgW[l * 32768 + (c & 127) * 256 + ((c >> 7) << 7) + k];
    } else if (id < 131072) {               // updWt[l][k][o]
      int e = id - 98304;
      int l = e >> 14, rr = e & 16383;
      int k = rr >> 7, oo = rr & 127;
      p.updWt[e] = p.updW[l * 16384 + oo * 128 + k];
    } else {                                // hW1t[k][o]
      int e = id - 131072;
      int k = e >> 7, oo = e & 127;
      p.hW1t[e] = p.hW1[oo * 128 + k];
    }
  }
  grid.sync();

  // ---- S1: encoder ---------------------------------------------------------
  {
    int idx = tid * 4, r = idx >> 8, d = idx & 255;
    const float* src = (d < 128) ? p.theta + (m0 + r) * 128 + d
                                 : p.cell + (m0 + r) * 128 + (d - 128);
    *reinterpret_cast<float4*>(&xs[r][d]) = *reinterpret_cast<const float4*>(src);
  }
  __syncthreads();
  {
    float a0 = 0.f, a1 = 0.f;
#pragma unroll 8
    for (int k = 0; k < 256; ++k) {
      float w = p.encWt[k * 128 + o];
      a0 += w * xs[r0][k];
      a1 += w * xs[r0 + 1][k];
    }
    float bb = p.encb[o];
    hs[r0][o] = fmaxf(a0 + bb, 0.f);
    hs[r0 + 1][o] = fmaxf(a1 + bb, 0.f);
  }
  __syncthreads();

  // ---- per-layer pieces ----------------------------------------------------
  auto pjpi = [&](const float* Mtl, float* pjX) {
    const int c = tid & 255;
    const int rr0 = (tid >> 8) * 4;  // 2 groups x 4 rows
    float a[4] = {0.f, 0.f, 0.f, 0.f};
#pragma unroll 8
    for (int k = 0; k < 128; ++k) {
      float w = Mtl[k * 256 + c];
      a[0] += w * hs[rr0][k];
      a[1] += w * hs[rr0 + 1][k];
      a[2] += w * hs[rr0 + 2][k];
      a[3] += w * hs[rr0 + 3][k];
    }
    if (c < 128) {
#pragma unroll
      for (int i = 0; i < 4; ++i) pjX[(m0 + rr0 + i) * Hc + c] = a[i];
    } else {
#pragma unroll
      for (int i = 0; i < 4; ++i) pis[rr0 + i][c - 128] = a[i];
    }
  };

  // agg + upd: reads pjX (global, all rows of batch) + pis/hs (LDS)
  auto agg_upd = [&](const float* pjX, const float* mbl, const float* updWtl,
                     const float* updbl) {
    const float* pjb = pjX + b * Nc * Hc;
    const float mbo = mbl[o];
    float s0 = pis[r0][o] + mbo;
    float s1 = pis[r0 + 1][o] + mbo;
    float vsum = 0.f, ab0 = 0.f, ab1 = 0.f;
#pragma unroll 8
    for (int j = 0; j < Nc; ++j) {
      float v = pjb[j * Hc + o];  // coalesced, L2-hot
      vsum += v;
      ab0 += fabsf(v + s0);
      ab1 += fabsf(v + s1);
    }
    float d0 = fmaxf(pjX[(m0 + r0) * Hc + o] + s0, 0.f);
    float d1 = fmaxf(pjX[(m0 + r0 + 1) * Hc + o] + s1, 0.f);
    // sum_j relu(v+s) = 0.5*(sum v + 256*s + sum|v+s|)
    xs[r0][o] = hs[r0][o] + (0.5f * (vsum + 256.f * s0 + ab0) - d0) * (1.f / 255.f);
    xs[r0 + 1][o] =
        hs[r0 + 1][o] + (0.5f * (vsum + 256.f * s1 + ab1) - d1) * (1.f / 255.f);
    __syncthreads();  // xs complete; all hs/pis reads done
    float a0 = 0.f, a1 = 0.f;
#pragma unroll 8
    for (int k = 0; k < 128; ++k) {
      float w = updWtl[k * 128 + o];
      a0 += w * xs[r0][k];
      a1 += w * xs[r0 + 1][k];
    }
    float bo = updbl[o];
    hs[r0][o] = fmaxf(a0 + bo, 0.f);
    hs[r0 + 1][o] = fmaxf(a1 + bo, 0.f);
    __syncthreads();  // new h ready
  };

  // ---- layer 0 -------------------------------------------------------------
  pjpi(p.Mt, p.pjA);
  grid.sync();  // pjA visible grid-wide (also orders LDS pis within block)
  agg_upd(p.pjA, p.msgb, p.updWt, p.updb);

  // ---- layer 1 -------------------------------------------------------------
  pjpi(p.Mt + 32768, p.pjB);
  grid.sync();
  agg_upd(p.pjB, p.msgb + Hc, p.updWt + 16384, p.updb + Hc);

  // ---- head ----------------------------------------------------------------
  {
    float a0 = 0.f, a1 = 0.f;
#pragma unroll 8
    for (int k = 0; k < 128; ++k) {
      float w = p.hW1t[k * 128 + o];
      a0 += w * hs[r0][k];
      a1 += w * hs[r0 + 1][k];
    }
    float bo = p.hb1[o];
    zs[r0][o] = fmaxf(a0 + bo, 0.f);
    zs[r0 + 1][o] = fmaxf(a1 + bo, 0.f);
  }
  __syncthreads();
  if (tid < R * Ac) {  // 40 dots of length 128
    const int r = tid / Ac;
    const int a = tid % Ac;
    const float* wr2 = p.hW2 + a * Hc;
    float sacc = 0.f;
#pragma unroll 4
    for (int k = 0; k < 128; k += 4) {
      float4 w = *reinterpret_cast<const float4*>(wr2 + k);
      sacc += w.x * zs[r][k] + w.y * zs[r][k + 1] + w.z * zs[r][k + 2] +
              w.w * zs[r][k + 3];
    }
    p.out[(m0 + r) * Ac + a] = sacc + p.hb2[a];
  }
}

// ---------------------------------------------------------------------------
extern "C" void kernel_launch(void* const* d_in, const int* in_sizes, int n_in,
                              void* d_out, int out_size, void* d_ws, size_t ws_size,
                              hipStream_t stream) {
  float* ws = (float*)d_ws;
  const int MH = Mc * Hc;  // 262144

  P p;
  p.theta = (const float*)d_in[0];
  p.cell  = (const float*)d_in[1];
  p.encW  = (const float*)d_in[2];
  p.encb  = (const float*)d_in[3];
  p.msgW  = (const float*)d_in[4];
  p.msgb  = (const float*)d_in[5];
  p.updW  = (const float*)d_in[6];
  p.updb  = (const float*)d_in[7];
  p.hW1   = (const float*)d_in[8];
  p.hb1   = (const float*)d_in[9];
  p.hW2   = (const float*)d_in[10];
  p.hb2   = (const float*)d_in[11];
  p.out   = (float*)d_out;
  p.pjA   = ws;
  p.pjB   = ws + MH;
  p.encWt = ws + 2 * MH;        // 32768
  p.Mt    = p.encWt + 32768;    // 2*32768
  p.updWt = p.Mt + 65536;       // 2*16384
  p.hW1t  = p.updWt + 32768;    // 16384

  void* args[] = {&p};
  hipLaunchCooperativeKernel((void*)fused, dim3(Mc / R), dim3(512), args, 0,
                             stream);
}

// Round 7
// 76.926 us; speedup vs baseline: 2.1007x; 2.1007x over previous
//
#include <hip/hip_runtime.h>
#include <hip/hip_bf16.h>

// AgentModel: B=8, N=256, TD=128, LH=128, H=128, A=5, L=2
constexpr int Nc = 256;
constexpr int Hc = 128;
constexpr int Ac = 5;
constexpr int Mc = 2048;
constexpr int R = 4;          // rows per block
constexpr int GRID = Mc / R;  // 512 blocks -> 2 blocks/CU

// ---------------------------------------------------------------------------
// K1: enc + pjpi(layer0).  Block: 4 rows x 256 threads.
// ---------------------------------------------------------------------------
__global__ __launch_bounds__(256, 2) void k1(
    const float* __restrict__ theta, const float* __restrict__ cell,
    const float* __restrict__ encW, const float* __restrict__ encb,
    const float* __restrict__ msgW0, float* __restrict__ h,
    float* __restrict__ pj, float* __restrict__ pi) {
  __shared__ float xs[R][256];
  __shared__ float hs[R][Hc];
  const int m0 = blockIdx.x * R;
  const int tid = threadIdx.x;

  {  // stage x = [theta|cell]: 4x256 floats = 256 threads x float4
    int idx = tid * 4, r = idx >> 8, d = idx & 255;
    const float* src = (d < 128) ? theta + (m0 + r) * 128 + d
                                 : cell + (m0 + r) * 128 + (d - 128);
    *reinterpret_cast<float4*>(&xs[r][d]) = *reinterpret_cast<const float4*>(src);
  }
  __syncthreads();

  const int o = tid & 127;
  const int rg = tid >> 7;  // 2 groups x 2 rows
  {                         // encoder
    const int r0 = rg * 2;
    float a0 = 0.f, a1 = 0.f;
    const float* wr = encW + o * 256;
#pragma unroll 8
    for (int k = 0; k < 256; k += 4) {
      float4 w = *reinterpret_cast<const float4*>(wr + k);
      a0 += w.x * xs[r0][k] + w.y * xs[r0][k + 1] + w.z * xs[r0][k + 2] +
            w.w * xs[r0][k + 3];
      a1 += w.x * xs[r0 + 1][k] + w.y * xs[r0 + 1][k + 1] +
            w.z * xs[r0 + 1][k + 2] + w.w * xs[r0 + 1][k + 3];
    }
    float b = encb[o];
    float v0 = fmaxf(a0 + b, 0.f), v1 = fmaxf(a1 + b, 0.f);
    hs[r0][o] = v0;
    hs[r0 + 1][o] = v1;
    h[(m0 + r0) * Hc + o] = v0;
    h[(m0 + r0 + 1) * Hc + o] = v1;
  }
  __syncthreads();

  {  // pj/pi layer0: 256 cols x 4 rows
    const int c = tid;
    const float* wr = msgW0 + (c & 127) * 256 + ((c >> 7) << 7);
    float a[R] = {0.f, 0.f, 0.f, 0.f};
#pragma unroll 8
    for (int k = 0; k < 128; k += 4) {
      float4 w = *reinterpret_cast<const float4*>(wr + k);
#pragma unroll
      for (int r = 0; r < R; ++r)
        a[r] += w.x * hs[r][k] + w.y * hs[r][k + 1] + w.z * hs[r][k + 2] +
                w.w * hs[r][k + 3];
    }
    float* dst = (c < 128) ? pj : pi;
    const int oc = c & 127;
#pragma unroll
    for (int r = 0; r < R; ++r) dst[(m0 + r) * Hc + oc] = a[r];
  }
}

// ---------------------------------------------------------------------------
// K2/K3: agg(l)+upd(l) [+ pjpi(l+1) | + head]
// agg: thread = (row-pair rp, o-quad q, j-quarter jq); float4 loads give
// 8 elems/load. sum_j relu(v+s) = 0.5*(sum v + 256*s + sum|v+s|).
// Partials reduced through LDS by the jq==0 threads.
// ---------------------------------------------------------------------------
template <bool LAST>
__global__ __launch_bounds__(256, 2) void k23(
    const float* __restrict__ pj, const float* __restrict__ pi,
    const float* __restrict__ mb, float* __restrict__ h,
    const float* __restrict__ updWl, const float* __restrict__ updbl,
    const float* __restrict__ msgW2, float* __restrict__ pj2,
    float* __restrict__ pi2, const float* __restrict__ hW1,
    const float* __restrict__ hb1, const float* __restrict__ hW2,
    const float* __restrict__ hb2, float* __restrict__ out) {
  __shared__ float part[3][64][13];  // jq 1..3 partials: vs[4],ab0[4],ab1[4]
  __shared__ float xs[R][Hc];        // h + agg
  __shared__ float hs[R][Hc];        // updated h; reused as z for head
  const int m0 = blockIdx.x * R;
  const int b = m0 >> 8;
  const int i0 = m0 & 255;  // row base within batch
  const int tid = threadIdx.x;
  const float* pjb = pj + b * Nc * Hc;

  {  // ---- aggregation ----
    const int jq = tid >> 6;         // 0..3
    const int unit = tid & 63;       // (rp,q)
    const int rp = unit >> 5;        // 0..1 -> rows rp*2, rp*2+1
    const int q = unit & 31;         // o-quad
    const int o4 = q * 4;
    const int r0 = rp * 2;

    float s0[4], s1[4];
    {
      float4 p0 = *reinterpret_cast<const float4*>(pi + (m0 + r0) * Hc + o4);
      float4 p1 = *reinterpret_cast<const float4*>(pi + (m0 + r0 + 1) * Hc + o4);
      float4 mm = *reinterpret_cast<const float4*>(mb + o4);
      s0[0] = p0.x + mm.x; s0[1] = p0.y + mm.y; s0[2] = p0.z + mm.z; s0[3] = p0.w + mm.w;
      s1[0] = p1.x + mm.x; s1[1] = p1.y + mm.y; s1[2] = p1.z + mm.z; s1[3] = p1.w + mm.w;
    }
    float vs[4] = {0.f, 0.f, 0.f, 0.f};
    float ab0[4] = {0.f, 0.f, 0.f, 0.f};
    float ab1[4] = {0.f, 0.f, 0.f, 0.f};
    const int j0 = jq * 64;
#pragma unroll 4
    for (int j = j0; j < j0 + 64; ++j) {
      float4 v4 = *reinterpret_cast<const float4*>(pjb + j * Hc + o4);
      float ve[4] = {v4.x, v4.y, v4.z, v4.w};
#pragma unroll
      for (int e = 0; e < 4; ++e) {
        vs[e] += ve[e];
        ab0[e] += fabsf(ve[e] + s0[e]);
        ab1[e] += fabsf(ve[e] + s1[e]);
      }
    }
    if (jq > 0) {
      float* pp = &part[jq - 1][unit][0];
#pragma unroll
      for (int e = 0; e < 4; ++e) {
        pp[e] = vs[e];
        pp[4 + e] = ab0[e];
        pp[8 + e] = ab1[e];
      }
    }
    __syncthreads();
    if (jq == 0) {
#pragma unroll
      for (int p = 0; p < 3; ++p) {
        const float* pp = &part[p][unit][0];
#pragma unroll
        for (int e = 0; e < 4; ++e) {
          vs[e] += pp[e];
          ab0[e] += pp[4 + e];
          ab1[e] += pp[8 + e];
        }
      }
      // epilogue: diag, combine, + h
      float4 pd0 = *reinterpret_cast<const float4*>(pjb + (i0 + r0) * Hc + o4);
      float4 pd1 = *reinterpret_cast<const float4*>(pjb + (i0 + r0 + 1) * Hc + o4);
      float4 h0 = *reinterpret_cast<const float4*>(h + (m0 + r0) * Hc + o4);
      float4 h1 = *reinterpret_cast<const float4*>(h + (m0 + r0 + 1) * Hc + o4);
      float pd0e[4] = {pd0.x, pd0.y, pd0.z, pd0.w};
      float pd1e[4] = {pd1.x, pd1.y, pd1.z, pd1.w};
      float h0e[4] = {h0.x, h0.y, h0.z, h0.w};
      float h1e[4] = {h1.x, h1.y, h1.z, h1.w};
#pragma unroll
      for (int e = 0; e < 4; ++e) {
        float d0 = fmaxf(pd0e[e] + s0[e], 0.f);
        float d1 = fmaxf(pd1e[e] + s1[e], 0.f);
        float sr0 = 0.5f * (vs[e] + 256.f * s0[e] + ab0[e]);
        float sr1 = 0.5f * (vs[e] + 256.f * s1[e] + ab1[e]);
        xs[r0][o4 + e] = h0e[e] + (sr0 - d0) * (1.f / 255.f);
        xs[r0 + 1][o4 + e] = h1e[e] + (sr1 - d1) * (1.f / 255.f);
      }
    }
  }
  __syncthreads();

  const int o = tid & 127;
  const int rg = tid >> 7;
  {  // ---- update GEMM ----
    const int r0 = rg * 2;
    float a0 = 0.f, a1 = 0.f;
    const float* wr = updWl + o * Hc;
#pragma unroll 8
    for (int k = 0; k < 128; k += 4) {
      float4 w = *reinterpret_cast<const float4*>(wr + k);
      a0 += w.x * xs[r0][k] + w.y * xs[r0][k + 1] + w.z * xs[r0][k + 2] +
            w.w * xs[r0][k + 3];
      a1 += w.x * xs[r0 + 1][k] + w.y * xs[r0 + 1][k + 1] +
            w.z * xs[r0 + 1][k + 2] + w.w * xs[r0 + 1][k + 3];
    }
    float bo = updbl[o];
    float v0 = fmaxf(a0 + bo, 0.f), v1 = fmaxf(a1 + bo, 0.f);
    hs[r0][o] = v0;
    hs[r0 + 1][o] = v1;
    if (!LAST) {
      h[(m0 + r0) * Hc + o] = v0;
      h[(m0 + r0 + 1) * Hc + o] = v1;
    }
  }
  __syncthreads();

  if (!LAST) {  // ---- pj/pi next layer ----
    const int c = tid;
    const float* wr = msgW2 + (c & 127) * 256 + ((c >> 7) << 7);
    float a[R] = {0.f, 0.f, 0.f, 0.f};
#pragma unroll 8
    for (int k = 0; k < 128; k += 4) {
      float4 w = *reinterpret_cast<const float4*>(wr + k);
#pragma unroll
      for (int r = 0; r < R; ++r)
        a[r] += w.x * hs[r][k] + w.y * hs[r][k + 1] + w.z * hs[r][k + 2] +
                w.w * hs[r][k + 3];
    }
    float* dst = (c < 128) ? pj2 : pi2;
    const int oc = c & 127;
#pragma unroll
    for (int r = 0; r < R; ++r) dst[(m0 + r) * Hc + oc] = a[r];
  } else {  // ---- head ----
    const int r0 = rg * 2;
    float a0 = 0.f, a1 = 0.f;
    const float* wr = hW1 + o * Hc;
#pragma unroll 8
    for (int k = 0; k < 128; k += 4) {
      float4 w = *reinterpret_cast<const float4*>(wr + k);
      a0 += w.x * hs[r0][k] + w.y * hs[r0][k + 1] + w.z * hs[r0][k + 2] +
            w.w * hs[r0][k + 3];
      a1 += w.x * hs[r0 + 1][k] + w.y * hs[r0 + 1][k + 1] +
            w.z * hs[r0 + 1][k + 2] + w.w * hs[r0 + 1][k + 3];
    }
    float bo = hb1[o];
    float z0 = fmaxf(a0 + bo, 0.f), z1 = fmaxf(a1 + bo, 0.f);
    __syncthreads();  // hs reads done; safe to overwrite as z
    xs[r0][o] = z0;
    xs[r0 + 1][o] = z1;
    __syncthreads();

    if (tid < R * Ac) {  // 20 dots of length 128
      const int r = tid / Ac;
      const int a = tid % Ac;
      const float* wr2 = hW2 + a * Hc;
      float sacc = 0.f;
#pragma unroll 8
      for (int k = 0; k < 128; k += 4) {
        float4 w = *reinterpret_cast<const float4*>(wr2 + k);
        sacc += w.x * xs[r][k] + w.y * xs[r][k + 1] + w.z * xs[r][k + 2] +
                w.w * xs[r][k + 3];
      }
      out[(m0 + r) * Ac + a] = sacc + hb2[a];
    }
  }
}

// ---------------------------------------------------------------------------
extern "C" void kernel_launch(void* const* d_in, const int* in_sizes, int n_in,
                              void* d_out, int out_size, void* d_ws, size_t ws_size,
                              hipStream_t stream) {
  const float* theta = (const float*)d_in[0];
  const float* cell  = (const float*)d_in[1];
  const float* encW  = (const float*)d_in[2];
  const float* encb  = (const float*)d_in[3];
  const float* msgW  = (const float*)d_in[4];   // (2,128,256)
  const float* msgb  = (const float*)d_in[5];   // (2,128)
  const float* updW  = (const float*)d_in[6];   // (2,128,128)
  const float* updb  = (const float*)d_in[7];   // (2,128)
  const float* hW1   = (const float*)d_in[8];
  const float* hb1   = (const float*)d_in[9];
  const float* hW2   = (const float*)d_in[10];
  const float* hb2   = (const float*)d_in[11];
  float* out = (float*)d_out;

  float* ws = (float*)d_ws;
  const int MH = Mc * Hc;  // 262144
  float* h   = ws;
  float* pjA = ws + MH;
  float* piA = ws + 2 * MH;
  float* pjB = ws + 3 * MH;
  float* piB = ws + 4 * MH;

  k1<<<GRID, 256, 0, stream>>>(theta, cell, encW, encb, msgW, h, pjA, piA);
  k23<false><<<GRID, 256, 0, stream>>>(pjA, piA, msgb, h, updW, updb,
                                       msgW + 32768, pjB, piB, hW1, hb1, hW2,
                                       hb2, out);
  k23<true><<<GRID, 256, 0, stream>>>(pjB, piB, msgb + Hc, h, updW + 16384,
                                      updb + Hc, nullptr, nullptr, nullptr,
                                      hW1, hb1, hW2, hb2, out);
}

// Round 8
// 76.821 us; speedup vs baseline: 2.1036x; 1.0014x over previous
//
#include <hip/hip_runtime.h>
#include <hip/hip_bf16.h>

// AgentModel: B=8, N=256, TD=128, LH=128, H=128, A=5, L=2
constexpr int Nc = 256;
constexpr int Hc = 128;
constexpr int Ac = 5;
constexpr int Mc = 2048;
constexpr int R = 8;  // rows per block; grid = 256 = 1 block/CU

// ---------------------------------------------------------------------------
// K1: encoder + pj/pi of layer 0.  256 blocks x 512 threads.
// ---------------------------------------------------------------------------
__global__ __launch_bounds__(512) void k1_enc_pjpi(
    const float* __restrict__ theta, const float* __restrict__ cell,
    const float* __restrict__ encW, const float* __restrict__ encb,
    const float* __restrict__ msgW0, float* __restrict__ h,
    float* __restrict__ pj, float* __restrict__ pi) {
  __shared__ float xs[R][256];
  __shared__ float hs[R][Hc];
  const int m0 = blockIdx.x * R;
  const int tid = threadIdx.x;

  {  // stage x = [theta|cell]: 512 threads x float4 = 2048 = 8*256 exactly
    int idx = tid * 4, r = idx >> 8, d = idx & 255;
    const float* src = (d < 128) ? theta + (m0 + r) * 128 + d
                                 : cell + (m0 + r) * 128 + (d - 128);
    *reinterpret_cast<float4*>(&xs[r][d]) = *reinterpret_cast<const float4*>(src);
  }
  __syncthreads();

  const int o = tid & 127;
  const int rg = tid >> 7;  // 0..3 -> rows rg*2, rg*2+1
  {                         // encoder; 64 float4 loads, 8 in flight x unroll
    const int r0 = rg * 2;
    float a0 = 0.f, a1 = 0.f;
    const float* wr = encW + o * 256;
#pragma unroll 8
    for (int k = 0; k < 256; k += 4) {
      float4 w = *reinterpret_cast<const float4*>(wr + k);
      a0 += w.x * xs[r0][k] + w.y * xs[r0][k + 1] + w.z * xs[r0][k + 2] +
            w.w * xs[r0][k + 3];
      a1 += w.x * xs[r0 + 1][k] + w.y * xs[r0 + 1][k + 1] +
            w.z * xs[r0 + 1][k + 2] + w.w * xs[r0 + 1][k + 3];
    }
    float b = encb[o];
    float v0 = fmaxf(a0 + b, 0.f), v1 = fmaxf(a1 + b, 0.f);
    hs[r0][o] = v0;
    hs[r0 + 1][o] = v1;
    h[(m0 + r0) * Hc + o] = v0;
    h[(m0 + r0 + 1) * Hc + o] = v1;
  }
  __syncthreads();

  {  // pj/pi layer 0: 256 cols x 2 rowgroups of 4 rows
    const int c = tid & 255;
    const int rg2 = tid >> 8;  // 0..1
    const int r0 = rg2 * 4;
    const float* wr = msgW0 + (c & 127) * 256 + ((c >> 7) << 7);
    float a[4] = {0.f, 0.f, 0.f, 0.f};
#pragma unroll 8
    for (int k = 0; k < 128; k += 4) {
      float4 w = *reinterpret_cast<const float4*>(wr + k);
#pragma unroll
      for (int r = 0; r < 4; ++r)
        a[r] += w.x * hs[r0 + r][k] + w.y * hs[r0 + r][k + 1] +
                w.z * hs[r0 + r][k + 2] + w.w * hs[r0 + r][k + 3];
    }
    float* dst = (c < 128) ? pj : pi;
    const int oc = c & 127;
#pragma unroll
    for (int r = 0; r < 4; ++r) dst[(m0 + r0 + r) * Hc + oc] = a[r];
  }
}

// ---------------------------------------------------------------------------
// K2/K3: agg(l)+upd(l) [+ pjpi(l+1) | + head]
// agg: sum_j relu(v+s) = 0.5*(sum v + 256*s + sum|v+s|); 32-deep register
// staging of pj loads for MLP (32 outstanding/wave).
// ---------------------------------------------------------------------------
template <bool LAST>
__global__ __launch_bounds__(512) void k_layer(
    const float* __restrict__ pj, const float* __restrict__ pi,
    const float* __restrict__ mb, float* __restrict__ h,
    const float* __restrict__ updWl, const float* __restrict__ updbl,
    const float* __restrict__ msgW2, float* __restrict__ pj2,
    float* __restrict__ pi2, const float* __restrict__ hW1,
    const float* __restrict__ hb1, const float* __restrict__ hW2,
    const float* __restrict__ hb2, float* __restrict__ out) {
  __shared__ float xs[R][Hc];  // h + agg
  __shared__ float hs[R][Hc];  // updated h
  __shared__ float zs[R][Hc];  // head z (LAST only)
  const int m0 = blockIdx.x * R;
  const int b = m0 >> 8;
  const int tid = threadIdx.x;
  const int o = tid & 127;
  const int rg = tid >> 7;  // 0..3 -> rows rg*2, rg*2+1
  const float* pjb = pj + b * Nc * Hc;

  {  // ---- aggregation ----
    const int r0 = rg * 2;
    const float mbo = mb[o];
    float s0 = pi[(m0 + r0) * Hc + o] + mbo;
    float s1 = pi[(m0 + r0 + 1) * Hc + o] + mbo;
    float vsum = 0.f, ab0 = 0.f, ab1 = 0.f;
    for (int jc = 0; jc < Nc; jc += 32) {
      float v[32];
#pragma unroll
      for (int i = 0; i < 32; ++i) v[i] = pjb[(jc + i) * Hc + o];
#pragma unroll
      for (int i = 0; i < 32; ++i) {
        vsum += v[i];
        ab0 += fabsf(v[i] + s0);
        ab1 += fabsf(v[i] + s1);
      }
    }
    float d0 = fmaxf(pj[(m0 + r0) * Hc + o] + s0, 0.f);
    float d1 = fmaxf(pj[(m0 + r0 + 1) * Hc + o] + s1, 0.f);
    float sr0 = 0.5f * (vsum + 256.f * s0 + ab0);
    float sr1 = 0.5f * (vsum + 256.f * s1 + ab1);
    xs[r0][o] = h[(m0 + r0) * Hc + o] + (sr0 - d0) * (1.f / 255.f);
    xs[r0 + 1][o] = h[(m0 + r0 + 1) * Hc + o] + (sr1 - d1) * (1.f / 255.f);
  }
  __syncthreads();

  {  // ---- update GEMM ----
    const int r0 = rg * 2;
    float a0 = 0.f, a1 = 0.f;
    const float* wr = updWl + o * Hc;
#pragma unroll 8
    for (int k = 0; k < 128; k += 4) {
      float4 w = *reinterpret_cast<const float4*>(wr + k);
      a0 += w.x * xs[r0][k] + w.y * xs[r0][k + 1] + w.z * xs[r0][k + 2] +
            w.w * xs[r0][k + 3];
      a1 += w.x * xs[r0 + 1][k] + w.y * xs[r0 + 1][k + 1] +
            w.z * xs[r0 + 1][k + 2] + w.w * xs[r0 + 1][k + 3];
    }
    float bo = updbl[o];
    float v0 = fmaxf(a0 + bo, 0.f), v1 = fmaxf(a1 + bo, 0.f);
    hs[r0][o] = v0;
    hs[r0 + 1][o] = v1;
    if (!LAST) {
      h[(m0 + r0) * Hc + o] = v0;
      h[(m0 + r0 + 1) * Hc + o] = v1;
    }
  }
  __syncthreads();

  if (!LAST) {  // ---- pj/pi next layer ----
    const int c = tid & 255;
    const int rg2 = tid >> 8;
    const int r0 = rg2 * 4;
    const float* wr = msgW2 + (c & 127) * 256 + ((c >> 7) << 7);
    float a[4] = {0.f, 0.f, 0.f, 0.f};
#pragma unroll 8
    for (int k = 0; k < 128; k += 4) {
      float4 w = *reinterpret_cast<const float4*>(wr + k);
#pragma unroll
      for (int r = 0; r < 4; ++r)
        a[r] += w.x * hs[r0 + r][k] + w.y * hs[r0 + r][k + 1] +
                w.z * hs[r0 + r][k + 2] + w.w * hs[r0 + r][k + 3];
    }
    float* dst = (c < 128) ? pj2 : pi2;
    const int oc = c & 127;
#pragma unroll
    for (int r = 0; r < 4; ++r) dst[(m0 + r0 + r) * Hc + oc] = a[r];
  } else {  // ---- head ----
    const int r0 = rg * 2;
    float a0 = 0.f, a1 = 0.f;
    const float* wr = hW1 + o * Hc;
#pragma unroll 8
    for (int k = 0; k < 128; k += 4) {
      float4 w = *reinterpret_cast<const float4*>(wr + k);
      a0 += w.x * hs[r0][k] + w.y * hs[r0][k + 1] + w.z * hs[r0][k + 2] +
            w.w * hs[r0][k + 3];
      a1 += w.x * hs[r0 + 1][k] + w.y * hs[r0 + 1][k + 1] +
            w.z * hs[r0 + 1][k + 2] + w.w * hs[r0 + 1][k + 3];
    }
    float bo = hb1[o];
    zs[r0][o] = fmaxf(a0 + bo, 0.f);
    zs[r0 + 1][o] = fmaxf(a1 + bo, 0.f);
    __syncthreads();

    if (tid < R * Ac) {  // 40 dots of length 128
      const int r = tid / Ac;
      const int a = tid % Ac;
      const float* wr2 = hW2 + a * Hc;
      float sacc = 0.f;
#pragma unroll 8
      for (int k = 0; k < 128; k += 4) {
        float4 w = *reinterpret_cast<const float4*>(wr2 + k);
        sacc += w.x * zs[r][k] + w.y * zs[r][k + 1] + w.z * zs[r][k + 2] +
                w.w * zs[r][k + 3];
      }
      out[(m0 + r) * Ac + a] = sacc + hb2[a];
    }
  }
}

// ---------------------------------------------------------------------------
extern "C" void kernel_launch(void* const* d_in, const int* in_sizes, int n_in,
                              void* d_out, int out_size, void* d_ws, size_t ws_size,
                              hipStream_t stream) {
  const float* theta = (const float*)d_in[0];
  const float* cell  = (const float*)d_in[1];
  const float* encW  = (const float*)d_in[2];
  const float* encb  = (const float*)d_in[3];
  const float* msgW  = (const float*)d_in[4];   // (2,128,256)
  const float* msgb  = (const float*)d_in[5];   // (2,128)
  const float* updW  = (const float*)d_in[6];   // (2,128,128)
  const float* updb  = (const float*)d_in[7];   // (2,128)
  const float* hW1   = (const float*)d_in[8];
  const float* hb1   = (const float*)d_in[9];
  const float* hW2   = (const float*)d_in[10];
  const float* hb2   = (const float*)d_in[11];
  float* out = (float*)d_out;

  float* ws = (float*)d_ws;
  const int MH = Mc * Hc;  // 262144
  float* h   = ws;
  float* pjA = ws + MH;
  float* piA = ws + 2 * MH;
  float* pjB = ws + 3 * MH;
  float* piB = ws + 4 * MH;

  const int grid = Mc / R;  // 256
  k1_enc_pjpi<<<grid, 512, 0, stream>>>(theta, cell, encW, encb, msgW, h, pjA,
                                        piA);
  k_layer<false><<<grid, 512, 0, stream>>>(pjA, piA, msgb, h, updW, updb,
                                           msgW + 32768, pjB, piB, hW1, hb1,
                                           hW2, hb2, out);
  k_layer<true><<<grid, 512, 0, stream>>>(pjB, piB, msgb + Hc, h, updW + 16384,
                                          updb + Hc, nullptr, nullptr, nullptr,
                                          hW1, hb1, hW2, hb2, out);
}